// Round 1
// 258.623 us; speedup vs baseline: 1.0529x; 1.0529x over previous
//
#include <hip/hip_runtime.h>
#include <stdint.h>

// x (16,256,64,64) fp32; 32 groups; 8 heads; head dim 32. All I/O fp32.
// Intermediates bf16 in d_ws. GEMMs: bf16 MFMA 16x16x32, BK=64, swizzled
// coalesced global_load_lds staging, LDS-staged coalesced epilogue.
// Softmax folded into att: att = diag(1/l) * sum_n exp(k) v  (no max-sub; |k|<~6).
// R6: att2 rewritten as MFMA GEMM (M=32,N=32,K=4096 per bh) — direct global->reg
//     fragment loads (no LDS staging, no bank conflicts), exp in-register,
//     row-sums l via ones-fragment MFMA (same bf16 ek as numerator -> error cancels).
#define BATCH 16
#define CCH   256
#define NSP   4096
#define QKV_M 768

typedef unsigned short u16;
typedef short  short8 __attribute__((ext_vector_type(8)));   // 8 bf16 (4 VGPRs)
typedef float  f32x4  __attribute__((ext_vector_type(4)));

__device__ __forceinline__ float bf2f(u16 h) {
  union { unsigned int u; float f; } x; x.u = ((unsigned int)h) << 16; return x.f;
}
__device__ __forceinline__ u16 f2bf(float f) {
  union { float f; unsigned int u; } x; x.f = f;
  unsigned int r = 0x7fffu + ((x.u >> 16) & 1u);
  return (u16)((x.u + r) >> 16);
}

#define GLB(p) ((__attribute__((address_space(1))) void*)(p))
#define LDSP(p) ((__attribute__((address_space(3))) void*)(p))

// ------------------------------------------------ weights fp32 -> bf16
__global__ __launch_bounds__(256) void convw_kernel(const float* __restrict__ wq,
                                                    const float* __restrict__ wp,
                                                    u16* __restrict__ dst) {
  const int i = (blockIdx.x * 256 + threadIdx.x) * 4;
  float4 v = (i < 196608) ? *(const float4*)(wq + i)
                          : *(const float4*)(wp + (i - 196608));
  ushort4 o;
  o.x = f2bf(v.x); o.y = f2bf(v.y); o.z = f2bf(v.z); o.w = f2bf(v.w);
  *(ushort4*)(dst + i) = o;
}

// ------------------------------------------------ GroupNorm stats (+ zero att accum)
__global__ __launch_bounds__(256) void gn_stats(const float* __restrict__ x,
                                                float2* __restrict__ stats,
                                                float* __restrict__ att4) {
  const int blk = blockIdx.x;
  const int tid = threadIdx.x;
  // zero att accumulator: 128 heads * 1056 floats = 512 blocks * 264
  {
    float* az = att4 + (size_t)blk * 264;
    for (int i = tid; i < 264; i += 256) az[i] = 0.f;
  }
  const float4* xv = (const float4*)(x + (size_t)blk * 32768);
  float s = 0.f, ss = 0.f;
  for (int i = tid; i < 8192; i += 256) {
    float4 u = xv[i];
    s  += u.x + u.y + u.z + u.w;
    ss += u.x * u.x + u.y * u.y + u.z * u.z + u.w * u.w;
  }
#pragma unroll
  for (int off = 32; off > 0; off >>= 1) {
    s  += __shfl_down(s, off);
    ss += __shfl_down(ss, off);
  }
  __shared__ float red[8];
  const int wave = tid >> 6, lane = tid & 63;
  if (lane == 0) { red[wave * 2] = s; red[wave * 2 + 1] = ss; }
  __syncthreads();
  if (tid == 0) {
    const float S  = red[0] + red[2] + red[4] + red[6];
    const float SS = red[1] + red[3] + red[5] + red[7];
    const float mean = S * (1.f / 32768.f);
    const float var  = SS * (1.f / 32768.f) - mean * mean;
    stats[blk] = make_float2(mean, rsqrtf(var + 1e-5f));
  }
}

// ------------------------------------------------ GN apply + transpose
__global__ __launch_bounds__(256) void gn_apply_t(const float* __restrict__ x,
                                                  const float* __restrict__ gw,
                                                  const float* __restrict__ gb,
                                                  const float2* __restrict__ stats,
                                                  u16* __restrict__ xnT) {
  __shared__ u16 ls[64][72];                    // [c][n], pad 72
  const int b = blockIdx.z, c0 = blockIdx.y * 64, n0 = blockIdx.x * 64;
  const int tid = threadIdx.x;
#pragma unroll
  for (int r = 0; r < 4; ++r) {
    const int cc = (tid >> 4) + r * 16;
    const int nn = (tid & 15) * 4;
    const int c = c0 + cc;
    const float2 st = stats[b * 32 + (c >> 3)];
    const float wv = gw[c] * st.y;
    const float bv = gb[c] - st.x * wv;
    float4 u = *(const float4*)(x + ((size_t)b * CCH + c) * NSP + n0 + nn);
    ushort4 o;
    o.x = f2bf(u.x * wv + bv);
    o.y = f2bf(u.y * wv + bv);
    o.z = f2bf(u.z * wv + bv);
    o.w = f2bf(u.w * wv + bv);
    *(ushort4*)&ls[cc][nn] = o;
  }
  __syncthreads();
#pragma unroll
  for (int p = 0; p < 2; ++p) {
    const int idx = tid + p * 256;              // 0..511
    const int nn = idx >> 3;
    const int cb = (idx & 7) * 8;
    u16 tmp[8];
#pragma unroll
    for (int j = 0; j < 8; ++j) tmp[j] = ls[cb + j][nn];
    *(uint4*)(xnT + ((size_t)b * NSP + n0 + nn) * CCH + c0 + cb) = *(uint4*)tmp;
  }
}

// ------------------------------------------------ MFMA GEMM, BK=64, coalesced staging
// C[b][m][n] = sum_c A[m][c]*Bt[b][n][c]; A bf16 MxK(K=256), Bt bf16 NxK.
template <int OUTF32>
__global__ __launch_bounds__(256) void gemm_mfma(const u16* __restrict__ A,
                                                 const u16* __restrict__ Bt,
                                                 const float* __restrict__ bias,
                                                 void* __restrict__ Cm, int M) {
  __shared__ __align__(16) u16 smem[17408];     // 34816 B: staging 32KB / C-tile epi
  const int tid = threadIdx.x, wave = tid >> 6, lane = tid & 63;
  const int n0 = blockIdx.x * 128, m0 = blockIdx.y * 128, bz = blockIdx.z;
  const u16* Bb = Bt + (size_t)bz * (size_t)NSP * CCH;

  const int lrow = lane >> 3;                   // 0..7: row within 8-row group
  const int kcl  = ((lane & 7) ^ lrow) * 8;     // swizzled k element offset
  const u16* pA[4]; const u16* pB[4];
#pragma unroll
  for (int j = 0; j < 4; ++j) {
    const int row = j * 32 + wave * 8 + lrow;
    pA[j] = A  + (size_t)(m0 + row) * CCH + kcl;
    pB[j] = Bb + (size_t)(n0 + row) * CCH + kcl;
  }
  u16* lA = smem;                               // 1024 granules (16KB)
  u16* lB = smem + 8192;                        // 1024 granules (16KB)

  const int wm = wave >> 1, wn = wave & 1;
  f32x4 acc[4][4];
#pragma unroll
  for (int i = 0; i < 4; ++i)
#pragma unroll
    for (int j = 0; j < 4; ++j) acc[i][j] = (f32x4){0.f, 0.f, 0.f, 0.f};

  for (int it = 0; it < 4; ++it) {              // K = 256, BK = 64
#pragma unroll
    for (int j = 0; j < 4; ++j) {
      __builtin_amdgcn_global_load_lds(GLB(pA[j]), LDSP(lA + (j * 256 + wave * 64) * 8), 16, 0, 0);
      __builtin_amdgcn_global_load_lds(GLB(pB[j]), LDSP(lB + (j * 256 + wave * 64) * 8), 16, 0, 0);
      pA[j] += 64; pB[j] += 64;
    }
    __syncthreads();
#pragma unroll
    for (int w = 0; w < 2; ++w) {               // two 32-k windows
      const int kcf = w * 4 + (lane >> 4);
      short8 af[4], bfr[4];
#pragma unroll
      for (int mt = 0; mt < 4; ++mt) {
        const int row = wm * 64 + mt * 16 + (lane & 15);
        af[mt] = *(const short8*)&lA[(row * 8 + (kcf ^ (row & 7))) * 8];
      }
#pragma unroll
      for (int nt = 0; nt < 4; ++nt) {
        const int row = wn * 64 + nt * 16 + (lane & 15);
        bfr[nt] = *(const short8*)&lB[(row * 8 + (kcf ^ (row & 7))) * 8];
      }
#pragma unroll
      for (int mt = 0; mt < 4; ++mt)
#pragma unroll
        for (int nt = 0; nt < 4; ++nt)
          acc[mt][nt] = __builtin_amdgcn_mfma_f32_16x16x32_bf16(af[mt], bfr[nt], acc[mt][nt], 0, 0, 0);
    }
    __syncthreads();
  }

  // epilogue: C/D frag col=lane&15, row=(lane>>4)*4+reg
  if (!OUTF32) {
    u16* cl = smem;                             // [128][136] u16 (34816 B)
#pragma unroll
    for (int mt = 0; mt < 4; ++mt)
#pragma unroll
      for (int nt = 0; nt < 4; ++nt)
#pragma unroll
        for (int r = 0; r < 4; ++r) {
          const int row = wm * 64 + mt * 16 + (lane >> 4) * 4 + r;
          const int col = wn * 64 + nt * 16 + (lane & 15);
          cl[row * 136 + col] = f2bf(acc[mt][nt][r]);
        }
    __syncthreads();
    u16* C = (u16*)Cm + (size_t)bz * M * NSP;
#pragma unroll
    for (int j = 0; j < 8; ++j) {
      const int idx = tid + j * 256;            // 0..2047
      const int row = idx >> 4, chunk = idx & 15;
      *(uint4*)(C + (size_t)(m0 + row) * NSP + n0 + chunk * 8) =
          *(const uint4*)&cl[row * 136 + chunk * 8];
    }
  } else {
    float* clf = (float*)smem;                  // [64][132] fp32 per pass (33792 B)
    float* C = (float*)Cm + (size_t)bz * M * NSP;
#pragma unroll
    for (int pass = 0; pass < 2; ++pass) {
      if (wm == pass) {
#pragma unroll
        for (int mt = 0; mt < 4; ++mt)
#pragma unroll
          for (int nt = 0; nt < 4; ++nt)
#pragma unroll
            for (int r = 0; r < 4; ++r) {
              const int rl = mt * 16 + (lane >> 4) * 4 + r;   // 0..63
              const int col = wn * 64 + nt * 16 + (lane & 15);
              clf[rl * 132 + col] = acc[mt][nt][r] + bias[m0 + pass * 64 + rl];
            }
      }
      __syncthreads();
#pragma unroll
      for (int j = 0; j < 8; ++j) {
        const int idx = tid + j * 256;          // 0..2047
        const int row = idx >> 5, chunk = idx & 31;
        *(float4*)(C + (size_t)(m0 + pass * 64 + row) * NSP + n0 + chunk * 4) =
            *(const float4*)&clf[row * 132 + chunk * 4];
      }
      __syncthreads();
    }
  }
}

// ------------------------------------------------ att4 += exp(K) @ V^T via MFMA
// Per (b,h): att[32][32] = sum_n ek[d][n] v[e][n], l[d] = sum_n ek[d][n].
// GEMM M=32,N=32,K=4096. A-frag: lane holds row (lane&15), 8 contig n at
// (lane>>4)*8 — matches [d][n] memory layout directly: global->reg, no LDS
// staging. l via ones-fragment MFMA (sums the SAME bf16 ek as the numerator).
// grid (8 n-splits of 512, 8 h, 16 b); 4 waves/block, 128 n per wave.
__global__ __launch_bounds__(256, 4) void att2_kernel(const u16* __restrict__ qkv,
                                                      float* __restrict__ att4) {
  const int b = blockIdx.z, h = blockIdx.y;
  const int bh = b * 8 + h;
  const int tid = threadIdx.x, wave = tid >> 6, lane = tid & 63;
  const int n0 = blockIdx.x * 512 + wave * 128;
  const u16* kp = qkv + ((size_t)b * QKV_M + 256 + h * 32) * NSP;
  const u16* vp = qkv + ((size_t)b * QKV_M + 512 + h * 32) * NSP;
  const int r  = lane & 15;                     // frag row (A: d-row, B: e-row)
  const int kc = (lane >> 4) * 8;               // frag k-offset within 32-chunk

  f32x4 acc[2][2], accl[2];
#pragma unroll
  for (int i = 0; i < 2; ++i) {
    accl[i] = (f32x4){0.f, 0.f, 0.f, 0.f};
#pragma unroll
    for (int j = 0; j < 2; ++j) acc[i][j] = (f32x4){0.f, 0.f, 0.f, 0.f};
  }
  short8 ones;
#pragma unroll
  for (int j = 0; j < 8; ++j) ones[j] = (short)0x3F80;   // bf16 1.0

  const size_t base0 = (size_t)r * NSP + (size_t)(n0 + kc);
#pragma unroll
  for (int c = 0; c < 4; ++c) {                 // 4 chunks of 32 n
    const size_t off = base0 + (size_t)c * 32;
    short8 k0 = *(const short8*)(kp + off);
    short8 k1 = *(const short8*)(kp + off + (size_t)16 * NSP);
    short8 v0 = *(const short8*)(vp + off);
    short8 v1 = *(const short8*)(vp + off + (size_t)16 * NSP);
    short8 e0, e1;
#pragma unroll
    for (int j = 0; j < 8; ++j) {
      e0[j] = (short)f2bf(__expf(bf2f((u16)k0[j])));
      e1[j] = (short)f2bf(__expf(bf2f((u16)k1[j])));
    }
    acc[0][0] = __builtin_amdgcn_mfma_f32_16x16x32_bf16(e0, v0, acc[0][0], 0, 0, 0);
    acc[0][1] = __builtin_amdgcn_mfma_f32_16x16x32_bf16(e0, v1, acc[0][1], 0, 0, 0);
    acc[1][0] = __builtin_amdgcn_mfma_f32_16x16x32_bf16(e1, v0, acc[1][0], 0, 0, 0);
    acc[1][1] = __builtin_amdgcn_mfma_f32_16x16x32_bf16(e1, v1, acc[1][1], 0, 0, 0);
    accl[0]   = __builtin_amdgcn_mfma_f32_16x16x32_bf16(e0, ones, accl[0], 0, 0, 0);
    accl[1]   = __builtin_amdgcn_mfma_f32_16x16x32_bf16(e1, ones, accl[1], 0, 0, 0);
  }

  // cross-wave reduce in LDS (pad 34: bank = (2d+e)%32 -> max 2-way, free)
  __shared__ float ratt[4][32][34];
  __shared__ float rl[4][32];
  const int rq = lane >> 4;
#pragma unroll
  for (int dt = 0; dt < 2; ++dt) {
#pragma unroll
    for (int et = 0; et < 2; ++et)
#pragma unroll
      for (int j = 0; j < 4; ++j)
        ratt[wave][dt * 16 + rq * 4 + j][et * 16 + r] = acc[dt][et][j];
    if (r == 0)
#pragma unroll
      for (int j = 0; j < 4; ++j) rl[wave][dt * 16 + rq * 4 + j] = accl[dt][j];
  }
  __syncthreads();
  float* ap = att4 + (size_t)bh * 1056;
  for (int i = tid; i < 1024; i += 256) {
    const int d = i >> 5, e = i & 31;
    atomicAdd(&ap[i], ratt[0][d][e] + ratt[1][d][e] + ratt[2][d][e] + ratt[3][d][e]);
  }
  if (tid < 32)
    atomicAdd(&ap[1024 + tid], rl[0][tid] + rl[1][tid] + rl[2][tid] + rl[3][tid]);
}

// ------------------------------------------------ out = (att/l)^T @ q -> outT[b][n][c]
__global__ __launch_bounds__(256) void attout_kernel(const u16* __restrict__ qkv,
                                                     const float* __restrict__ att4,
                                                     u16* __restrict__ outT) {
  const int b = blockIdx.z, h = blockIdx.y;
  const int bh = b * 8 + h;
  const int n = blockIdx.x * 256 + threadIdx.x;
  const u16* q = qkv + ((size_t)b * QKV_M + h * 32) * NSP;
  const float* ap = att4 + (size_t)bh * 1056;
  __shared__ float as[32][33];
  for (int i = threadIdx.x; i < 1024; i += 256) {
    const int d = i >> 5;
    as[d][i & 31] = ap[i] / ap[1024 + d];       // fold softmax 1/l_d
  }
  __syncthreads();
  float qv[32];
#pragma unroll
  for (int d = 0; d < 32; ++d) qv[d] = bf2f(q[(size_t)d * NSP + n]);
  u16 ob[32];
#pragma unroll
  for (int e = 0; e < 32; ++e) {
    float acc = 0.f;
#pragma unroll
    for (int d = 0; d < 32; ++d) acc += as[d][e] * qv[d];
    ob[e] = f2bf(acc);
  }
  u16* orow = outT + ((size_t)b * NSP + n) * CCH + h * 32;
#pragma unroll
  for (int j = 0; j < 4; ++j) ((uint4*)orow)[j] = ((const uint4*)ob)[j];
}

// ------------------------------------------------ launch
extern "C" void kernel_launch(void* const* d_in, const int* in_sizes, int n_in,
                              void* d_out, int out_size, void* d_ws, size_t ws_size,
                              hipStream_t stream) {
  const float* x      = (const float*)d_in[0];
  const float* gn_w   = (const float*)d_in[1];
  const float* gn_b   = (const float*)d_in[2];
  const float* w_qkv  = (const float*)d_in[3];
  const float* w_proj = (const float*)d_in[4];
  const float* b_proj = (const float*)d_in[5];
  float* out = (float*)d_out;

  char* ws = (char*)d_ws;
  u16*    xnT   = (u16*)ws;                                 // 32 MiB [b][n][c]; reused as outT
  u16*    qkv   = (u16*)(ws + 33554432ull);                 // 96 MiB [b][768][n]
  float*  att4  = (float*)(ws + 134217728ull);              // 128*1056*4 = 540672 B
  float2* stats = (float2*)(ws + 134758400ull);             // 4 KiB
  u16*    wbf   = (u16*)(ws + 134762496ull);                // 512 KiB
  u16* wq_bf = wbf;
  u16* wp_bf = wbf + 196608;

  convw_kernel<<<256, 256, 0, stream>>>(w_qkv, w_proj, wbf);
  gn_stats<<<512, 256, 0, stream>>>(x, stats, att4);
  gn_apply_t<<<dim3(64, 4, 16), 256, 0, stream>>>(x, gn_w, gn_b, stats, xnT);
  gemm_mfma<0><<<dim3(32, 6, 16), 256, 0, stream>>>(wq_bf, xnT, nullptr, qkv, QKV_M);
  att2_kernel<<<dim3(8, 8, 16), 256, 0, stream>>>(qkv, att4);
  attout_kernel<<<dim3(16, 8, 16), 256, 0, stream>>>(qkv, att4, xnT); // xnT now outT
  gemm_mfma<1><<<dim3(32, 2, 16), 256, 0, stream>>>(wp_bf, xnT, b_proj, out, CCH);
}

// Round 2
// 234.343 us; speedup vs baseline: 1.1620x; 1.1036x over previous
//
#include <hip/hip_runtime.h>
#include <stdint.h>

// x (16,256,64,64) fp32; 32 groups; 8 heads; head dim 32. All I/O fp32.
// Intermediates bf16 in d_ws. GEMMs: bf16 MFMA 16x16x32, BK=64, swizzled
// coalesced global_load_lds staging, LDS-staged coalesced epilogue.
// Softmax folded into att: att = diag(1/l) * sum_n exp(k) v  (no max-sub; |k|<~6).
// R6: att2 as MFMA GEMM (M=32,N=32,K=4096 per bh), direct global->reg frags.
// R7: attout deleted — attention-output matrix folds into w_proj:
//     W2_b = wp @ blockdiag(att/l)  (per-batch 256x256, ~2us kernel), and
//     proj = W2_b @ q. QKV gemm writes Q rows TRANSPOSED (qT[b][n][d]) so the
//     final gemm consumes them directly. Saves attout's 57us + 64MiB traffic.
#define BATCH 16
#define CCH   256
#define NSP   4096
#define QKV_M 768

typedef unsigned short u16;
typedef short  short8 __attribute__((ext_vector_type(8)));   // 8 bf16 (4 VGPRs)
typedef float  f32x4  __attribute__((ext_vector_type(4)));

__device__ __forceinline__ float bf2f(u16 h) {
  union { unsigned int u; float f; } x; x.u = ((unsigned int)h) << 16; return x.f;
}
__device__ __forceinline__ u16 f2bf(float f) {
  union { float f; unsigned int u; } x; x.f = f;
  unsigned int r = 0x7fffu + ((x.u >> 16) & 1u);
  return (u16)((x.u + r) >> 16);
}

#define GLB(p) ((__attribute__((address_space(1))) void*)(p))
#define LDSP(p) ((__attribute__((address_space(3))) void*)(p))

// ------------------------------------------------ weights fp32 -> bf16
__global__ __launch_bounds__(256) void convw_kernel(const float* __restrict__ wq,
                                                    const float* __restrict__ wp,
                                                    u16* __restrict__ dst) {
  const int i = (blockIdx.x * 256 + threadIdx.x) * 4;
  float4 v = (i < 196608) ? *(const float4*)(wq + i)
                          : *(const float4*)(wp + (i - 196608));
  ushort4 o;
  o.x = f2bf(v.x); o.y = f2bf(v.y); o.z = f2bf(v.z); o.w = f2bf(v.w);
  *(ushort4*)(dst + i) = o;
}

// ------------------------------------------------ GroupNorm stats (+ zero att accum)
__global__ __launch_bounds__(256) void gn_stats(const float* __restrict__ x,
                                                float2* __restrict__ stats,
                                                float* __restrict__ att4) {
  const int blk = blockIdx.x;
  const int tid = threadIdx.x;
  // zero att accumulator: 128 heads * 1056 floats = 512 blocks * 264
  {
    float* az = att4 + (size_t)blk * 264;
    for (int i = tid; i < 264; i += 256) az[i] = 0.f;
  }
  const float4* xv = (const float4*)(x + (size_t)blk * 32768);
  float s = 0.f, ss = 0.f;
  for (int i = tid; i < 8192; i += 256) {
    float4 u = xv[i];
    s  += u.x + u.y + u.z + u.w;
    ss += u.x * u.x + u.y * u.y + u.z * u.z + u.w * u.w;
  }
#pragma unroll
  for (int off = 32; off > 0; off >>= 1) {
    s  += __shfl_down(s, off);
    ss += __shfl_down(ss, off);
  }
  __shared__ float red[8];
  const int wave = tid >> 6, lane = tid & 63;
  if (lane == 0) { red[wave * 2] = s; red[wave * 2 + 1] = ss; }
  __syncthreads();
  if (tid == 0) {
    const float S  = red[0] + red[2] + red[4] + red[6];
    const float SS = red[1] + red[3] + red[5] + red[7];
    const float mean = S * (1.f / 32768.f);
    const float var  = SS * (1.f / 32768.f) - mean * mean;
    stats[blk] = make_float2(mean, rsqrtf(var + 1e-5f));
  }
}

// ------------------------------------------------ GN apply + transpose
__global__ __launch_bounds__(256) void gn_apply_t(const float* __restrict__ x,
                                                  const float* __restrict__ gw,
                                                  const float* __restrict__ gb,
                                                  const float2* __restrict__ stats,
                                                  u16* __restrict__ xnT) {
  __shared__ u16 ls[64][72];                    // [c][n], pad 72
  const int b = blockIdx.z, c0 = blockIdx.y * 64, n0 = blockIdx.x * 64;
  const int tid = threadIdx.x;
#pragma unroll
  for (int r = 0; r < 4; ++r) {
    const int cc = (tid >> 4) + r * 16;
    const int nn = (tid & 15) * 4;
    const int c = c0 + cc;
    const float2 st = stats[b * 32 + (c >> 3)];
    const float wv = gw[c] * st.y;
    const float bv = gb[c] - st.x * wv;
    float4 u = *(const float4*)(x + ((size_t)b * CCH + c) * NSP + n0 + nn);
    ushort4 o;
    o.x = f2bf(u.x * wv + bv);
    o.y = f2bf(u.y * wv + bv);
    o.z = f2bf(u.z * wv + bv);
    o.w = f2bf(u.w * wv + bv);
    *(ushort4*)&ls[cc][nn] = o;
  }
  __syncthreads();
#pragma unroll
  for (int p = 0; p < 2; ++p) {
    const int idx = tid + p * 256;              // 0..511
    const int nn = idx >> 3;
    const int cb = (idx & 7) * 8;
    u16 tmp[8];
#pragma unroll
    for (int j = 0; j < 8; ++j) tmp[j] = ls[cb + j][nn];
    *(uint4*)(xnT + ((size_t)b * NSP + n0 + nn) * CCH + c0 + cb) = *(uint4*)tmp;
  }
}

// ------------------------------------------------ MFMA GEMM, BK=64, coalesced staging
// C[b][m][n] = sum_c A[m][c]*Bt[b][n][c]; A bf16 MxK(K=256), Bt bf16 NxK.
// OUTF32: fp32 output + bias. TRQ: rows m0<256 are written TRANSPOSED as
// qT[b][n][m] into the same C buffer (Q part of qkv), K/V rows unchanged.
template <int OUTF32, int TRQ>
__global__ __launch_bounds__(256) void gemm_mfma(const u16* __restrict__ A,
                                                 const u16* __restrict__ Bt,
                                                 const float* __restrict__ bias,
                                                 void* __restrict__ Cm, int M,
                                                 int aBatch, long btStride) {
  __shared__ __align__(16) u16 smem[17408];     // 34816 B: staging 32KB / C-tile epi
  const int tid = threadIdx.x, wave = tid >> 6, lane = tid & 63;
  const int n0 = blockIdx.x * 128, m0 = blockIdx.y * 128, bz = blockIdx.z;
  const u16* Ab = A + (size_t)bz * aBatch;
  const u16* Bb = Bt + (size_t)bz * btStride;

  const int lrow = lane >> 3;                   // 0..7: row within 8-row group
  const int kcl  = ((lane & 7) ^ lrow) * 8;     // swizzled k element offset
  const u16* pA[4]; const u16* pB[4];
#pragma unroll
  for (int j = 0; j < 4; ++j) {
    const int row = j * 32 + wave * 8 + lrow;
    pA[j] = Ab + (size_t)(m0 + row) * CCH + kcl;
    pB[j] = Bb + (size_t)(n0 + row) * CCH + kcl;
  }
  u16* lA = smem;                               // 1024 granules (16KB)
  u16* lB = smem + 8192;                        // 1024 granules (16KB)

  const int wm = wave >> 1, wn = wave & 1;
  f32x4 acc[4][4];
#pragma unroll
  for (int i = 0; i < 4; ++i)
#pragma unroll
    for (int j = 0; j < 4; ++j) acc[i][j] = (f32x4){0.f, 0.f, 0.f, 0.f};

  for (int it = 0; it < 4; ++it) {              // K = 256, BK = 64
#pragma unroll
    for (int j = 0; j < 4; ++j) {
      __builtin_amdgcn_global_load_lds(GLB(pA[j]), LDSP(lA + (j * 256 + wave * 64) * 8), 16, 0, 0);
      __builtin_amdgcn_global_load_lds(GLB(pB[j]), LDSP(lB + (j * 256 + wave * 64) * 8), 16, 0, 0);
      pA[j] += 64; pB[j] += 64;
    }
    __syncthreads();
#pragma unroll
    for (int w = 0; w < 2; ++w) {               // two 32-k windows
      const int kcf = w * 4 + (lane >> 4);
      short8 af[4], bfr[4];
#pragma unroll
      for (int mt = 0; mt < 4; ++mt) {
        const int row = wm * 64 + mt * 16 + (lane & 15);
        af[mt] = *(const short8*)&lA[(row * 8 + (kcf ^ (row & 7))) * 8];
      }
#pragma unroll
      for (int nt = 0; nt < 4; ++nt) {
        const int row = wn * 64 + nt * 16 + (lane & 15);
        bfr[nt] = *(const short8*)&lB[(row * 8 + (kcf ^ (row & 7))) * 8];
      }
#pragma unroll
      for (int mt = 0; mt < 4; ++mt)
#pragma unroll
        for (int nt = 0; nt < 4; ++nt)
          acc[mt][nt] = __builtin_amdgcn_mfma_f32_16x16x32_bf16(af[mt], bfr[nt], acc[mt][nt], 0, 0, 0);
    }
    __syncthreads();
  }

  // epilogue: C/D frag col=lane&15, row=(lane>>4)*4+reg
  if (!OUTF32) {
    u16* cl = smem;                             // [128][136] u16 (34816 B)
    const bool tr = TRQ && (m0 < 256);          // uniform per block
#pragma unroll
    for (int mt = 0; mt < 4; ++mt)
#pragma unroll
      for (int nt = 0; nt < 4; ++nt)
#pragma unroll
        for (int r = 0; r < 4; ++r) {
          const int row = wm * 64 + mt * 16 + (lane >> 4) * 4 + r;
          const int col = wn * 64 + nt * 16 + (lane & 15);
          if (tr) cl[col * 136 + row] = f2bf(acc[mt][nt][r]);   // tile stored n-major
          else    cl[row * 136 + col] = f2bf(acc[mt][nt][r]);
        }
    __syncthreads();
    u16* C = (u16*)Cm + (size_t)bz * M * NSP;
    if (tr) {
      // cl is [n_local][m]; write qT[b][n][m] rows: full 256B m-contig chunks
#pragma unroll
      for (int j = 0; j < 8; ++j) {
        const int idx = tid + j * 256;          // 0..2047
        const int nl = idx >> 4, mc = (idx & 15) * 8;
        *(uint4*)(C + (size_t)(n0 + nl) * CCH + m0 + mc) =
            *(const uint4*)&cl[nl * 136 + mc];
      }
    } else {
#pragma unroll
      for (int j = 0; j < 8; ++j) {
        const int idx = tid + j * 256;          // 0..2047
        const int row = idx >> 4, chunk = idx & 15;
        *(uint4*)(C + (size_t)(m0 + row) * NSP + n0 + chunk * 8) =
            *(const uint4*)&cl[row * 136 + chunk * 8];
      }
    }
  } else {
    float* clf = (float*)smem;                  // [64][132] fp32 per pass (33792 B)
    float* C = (float*)Cm + (size_t)bz * M * NSP;
#pragma unroll
    for (int pass = 0; pass < 2; ++pass) {
      if (wm == pass) {
#pragma unroll
        for (int mt = 0; mt < 4; ++mt)
#pragma unroll
          for (int nt = 0; nt < 4; ++nt)
#pragma unroll
            for (int r = 0; r < 4; ++r) {
              const int rl = mt * 16 + (lane >> 4) * 4 + r;   // 0..63
              const int col = wn * 64 + nt * 16 + (lane & 15);
              clf[rl * 132 + col] = acc[mt][nt][r] + bias[m0 + pass * 64 + rl];
            }
      }
      __syncthreads();
#pragma unroll
      for (int j = 0; j < 8; ++j) {
        const int idx = tid + j * 256;          // 0..2047
        const int row = idx >> 5, chunk = idx & 31;
        *(float4*)(C + (size_t)(m0 + pass * 64 + row) * NSP + n0 + chunk * 4) =
            *(const float4*)&clf[row * 132 + chunk * 4];
      }
      __syncthreads();
    }
  }
}

// ------------------------------------------------ att4 += exp(K) @ V^T via MFMA
// Per (b,h): att[32][32] = sum_n ek[d][n] v[e][n], l[d] = sum_n ek[d][n].
// GEMM M=32,N=32,K=4096. A-frag: lane holds row (lane&15), 8 contig n at
// (lane>>4)*8 — matches [d][n] memory layout directly: global->reg, no LDS
// staging. l via ones-fragment MFMA (sums the SAME bf16 ek as the numerator).
// grid (8 n-splits of 512, 8 h, 16 b); 4 waves/block, 128 n per wave.
__global__ __launch_bounds__(256, 4) void att2_kernel(const u16* __restrict__ qkv,
                                                      float* __restrict__ att4) {
  const int b = blockIdx.z, h = blockIdx.y;
  const int bh = b * 8 + h;
  const int tid = threadIdx.x, wave = tid >> 6, lane = tid & 63;
  const int n0 = blockIdx.x * 512 + wave * 128;
  const u16* kp = qkv + ((size_t)b * QKV_M + 256 + h * 32) * NSP;
  const u16* vp = qkv + ((size_t)b * QKV_M + 512 + h * 32) * NSP;
  const int r  = lane & 15;                     // frag row (A: d-row, B: e-row)
  const int kc = (lane >> 4) * 8;               // frag k-offset within 32-chunk

  f32x4 acc[2][2], accl[2];
#pragma unroll
  for (int i = 0; i < 2; ++i) {
    accl[i] = (f32x4){0.f, 0.f, 0.f, 0.f};
#pragma unroll
    for (int j = 0; j < 2; ++j) acc[i][j] = (f32x4){0.f, 0.f, 0.f, 0.f};
  }
  short8 ones;
#pragma unroll
  for (int j = 0; j < 8; ++j) ones[j] = (short)0x3F80;   // bf16 1.0

  const size_t base0 = (size_t)r * NSP + (size_t)(n0 + kc);
#pragma unroll
  for (int c = 0; c < 4; ++c) {                 // 4 chunks of 32 n
    const size_t off = base0 + (size_t)c * 32;
    short8 k0 = *(const short8*)(kp + off);
    short8 k1 = *(const short8*)(kp + off + (size_t)16 * NSP);
    short8 v0 = *(const short8*)(vp + off);
    short8 v1 = *(const short8*)(vp + off + (size_t)16 * NSP);
    short8 e0, e1;
#pragma unroll
    for (int j = 0; j < 8; ++j) {
      e0[j] = (short)f2bf(__expf(bf2f((u16)k0[j])));
      e1[j] = (short)f2bf(__expf(bf2f((u16)k1[j])));
    }
    acc[0][0] = __builtin_amdgcn_mfma_f32_16x16x32_bf16(e0, v0, acc[0][0], 0, 0, 0);
    acc[0][1] = __builtin_amdgcn_mfma_f32_16x16x32_bf16(e0, v1, acc[0][1], 0, 0, 0);
    acc[1][0] = __builtin_amdgcn_mfma_f32_16x16x32_bf16(e1, v0, acc[1][0], 0, 0, 0);
    acc[1][1] = __builtin_amdgcn_mfma_f32_16x16x32_bf16(e1, v1, acc[1][1], 0, 0, 0);
    accl[0]   = __builtin_amdgcn_mfma_f32_16x16x32_bf16(e0, ones, accl[0], 0, 0, 0);
    accl[1]   = __builtin_amdgcn_mfma_f32_16x16x32_bf16(e1, ones, accl[1], 0, 0, 0);
  }

  // cross-wave reduce in LDS (pad 34: bank = (2d+e)%32 -> max 2-way, free)
  __shared__ float ratt[4][32][34];
  __shared__ float rl[4][32];
  const int rq = lane >> 4;
#pragma unroll
  for (int dt = 0; dt < 2; ++dt) {
#pragma unroll
    for (int et = 0; et < 2; ++et)
#pragma unroll
      for (int j = 0; j < 4; ++j)
        ratt[wave][dt * 16 + rq * 4 + j][et * 16 + r] = acc[dt][et][j];
    if (r == 0)
#pragma unroll
      for (int j = 0; j < 4; ++j) rl[wave][dt * 16 + rq * 4 + j] = accl[dt][j];
  }
  __syncthreads();
  float* ap = att4 + (size_t)bh * 1056;
  for (int i = tid; i < 1024; i += 256) {
    const int d = i >> 5, e = i & 31;
    atomicAdd(&ap[i], ratt[0][d][e] + ratt[1][d][e] + ratt[2][d][e] + ratt[3][d][e]);
  }
  if (tid < 32)
    atomicAdd(&ap[1024 + tid], rl[0][tid] + rl[1][tid] + rl[2][tid] + rl[3][tid]);
}

// ------------------------------------------------ W2_b = wp @ blockdiag(att/l)
// W2[b][o][h*32+d] = sum_e wp[o][h*32+e] * att[bh][d][e]/l[bh][d].
// grid 256 = 16 b x 16 o-tiles; thread = output column c' = h*32+d.
__global__ __launch_bounds__(256) void w2_kernel(const u16* __restrict__ wp_bf,
                                                 const float* __restrict__ att4,
                                                 u16* __restrict__ W2) {
  const int b = blockIdx.x >> 4;
  const int o0 = (blockIdx.x & 15) * 16;
  const int tid = threadIdx.x;
  const int h = tid >> 5, d = tid & 31;
  const float* ap = att4 + ((size_t)b * 8 + h) * 1056;
  const float linv = 1.f / ap[1024 + d];
  float as[32];
#pragma unroll
  for (int e = 0; e < 32; ++e) as[e] = ap[d * 32 + e] * linv;
  u16* w2p = W2 + (size_t)b * 65536;
  for (int oi = 0; oi < 16; ++oi) {
    const int o = o0 + oi;
    const uint4* wr = (const uint4*)(wp_bf + o * 256 + h * 32);
    float acc = 0.f;
#pragma unroll
    for (int j = 0; j < 4; ++j) {
      uint4 u = wr[j];
      const u16* w8 = (const u16*)&u;
#pragma unroll
      for (int t = 0; t < 8; ++t) acc += bf2f(w8[t]) * as[j * 8 + t];
    }
    w2p[o * 256 + tid] = f2bf(acc);             // coalesced u16 row writes
  }
}

// ------------------------------------------------ launch
extern "C" void kernel_launch(void* const* d_in, const int* in_sizes, int n_in,
                              void* d_out, int out_size, void* d_ws, size_t ws_size,
                              hipStream_t stream) {
  const float* x      = (const float*)d_in[0];
  const float* gn_w   = (const float*)d_in[1];
  const float* gn_b   = (const float*)d_in[2];
  const float* w_qkv  = (const float*)d_in[3];
  const float* w_proj = (const float*)d_in[4];
  const float* b_proj = (const float*)d_in[5];
  float* out = (float*)d_out;

  char* ws = (char*)d_ws;
  u16*    xnT   = (u16*)ws;                                 // 32 MiB [b][n][c]; reused as W2 after QKV gemm
  u16*    qkv   = (u16*)(ws + 33554432ull);                 // 96 MiB [b][768][n] (Q part holds qT[b][n][256])
  float*  att4  = (float*)(ws + 134217728ull);              // 128*1056*4 = 540672 B
  float2* stats = (float2*)(ws + 134758400ull);             // 4 KiB
  u16*    wbf   = (u16*)(ws + 134762496ull);                // 512 KiB
  u16* wq_bf = wbf;
  u16* wp_bf = wbf + 196608;
  u16* W2 = xnT;                                            // 2 MiB, xnT free after QKV gemm

  convw_kernel<<<256, 256, 0, stream>>>(w_qkv, w_proj, wbf);
  gn_stats<<<512, 256, 0, stream>>>(x, stats, att4);
  gn_apply_t<<<dim3(64, 4, 16), 256, 0, stream>>>(x, gn_w, gn_b, stats, xnT);
  gemm_mfma<0, 1><<<dim3(32, 6, 16), 256, 0, stream>>>(wq_bf, xnT, nullptr, qkv,
                                                       QKV_M, 0, (long)NSP * CCH);
  att2_kernel<<<dim3(8, 8, 16), 256, 0, stream>>>(qkv, att4);
  w2_kernel<<<256, 256, 0, stream>>>(wp_bf, att4, W2);
  gemm_mfma<1, 0><<<dim3(32, 2, 16), 256, 0, stream>>>(W2, qkv, b_proj, out,
                                                       CCH, 65536, (long)QKV_M * NSP);
}